// Round 1
// 691.900 us; speedup vs baseline: 1.0052x; 1.0052x over previous
//
#include <hip/hip_runtime.h>

typedef short short8 __attribute__((ext_vector_type(8)));
typedef float v4f   __attribute__((ext_vector_type(4)));

#define N_NODES 50000
#define N_EDGES 1600000
#define DIM     512
#define SCAN_NB 49   // 49 blocks * 1024 elems = 50176 >= 50000

__device__ __forceinline__ float bf2f(unsigned short u) {
    unsigned int x = ((unsigned int)u) << 16;
    return __uint_as_float(x);
}
__device__ __forceinline__ unsigned int f2bfu(float f) {
    unsigned int x = __float_as_uint(f);
    unsigned int r = x + 0x7fffu + ((x >> 16) & 1u);   // RTNE
    return r >> 16;
}
// bf16 pair unpack straight from a dword (no ushort round-trip)
__device__ __forceinline__ float lo16(unsigned int u) { return __uint_as_float(u << 16); }
__device__ __forceinline__ float hi16(unsigned int u) { return __uint_as_float(u & 0xffff0000u); }

// ---------------- dtype detection --------------------------------------------
// flags[0] = 1 if float tensors are bf16 (else fp32)
// flags[1] = 1 if edge index tensors are int64 (else int32)
__global__ void detect_kernel(const unsigned int* __restrict__ xw,
                              const int* __restrict__ erow,
                              int* __restrict__ flags) {
    __shared__ int cbf, cz;
    if (threadIdx.x == 0) { cbf = 0; cz = 0; }
    __syncthreads();
    int lb = 0, lz = 0;
    for (int i = threadIdx.x; i < 1024; i += 256) {
        unsigned int w = xw[i];
        unsigned int e0 = (w >> 7) & 0xFFu;    // bf16 exponent of low half
        unsigned int e1 = (w >> 23) & 0xFFu;   // bf16 exponent of high half
        if (e0 >= 0x70u && e0 <= 0x8Fu && e1 >= 0x70u && e1 <= 0x8Fu) lb++;
        if (erow[2 * i + 1] == 0) lz++;
    }
    atomicAdd(&cbf, lb);
    atomicAdd(&cz, lz);
    __syncthreads();
    if (threadIdx.x == 0) {
        flags[0] = (cbf > 512) ? 1 : 0;
        flags[1] = (cz > 512) ? 1 : 0;
    }
}

// ---------------- X fp32 -> bf16 pre-convert (skipped if X already bf16) ------
__global__ __launch_bounds__(256) void convert_x(const void* __restrict__ Xv,
                                                 unsigned short* __restrict__ Xc,
                                                 const int* __restrict__ flags) {
    if (flags[0] != 0) return;   // data-dependent, stable across calls
    const float* Xf = (const float*)Xv;
    size_t i = ((size_t)blockIdx.x * 256 + threadIdx.x) * 8;
    float4 f0 = *(const float4*)(Xf + i);
    float4 f1 = *(const float4*)(Xf + i + 4);
    uint4 o;
    o.x = f2bfu(f0.x) | (f2bfu(f0.y) << 16);
    o.y = f2bfu(f0.z) | (f2bfu(f0.w) << 16);
    o.z = f2bfu(f1.x) | (f2bfu(f1.y) << 16);
    o.w = f2bfu(f1.z) | (f2bfu(f1.w) << 16);
    *(uint4*)(Xc + i) = o;
}

// ---------------- W transpose -> canonical bf16 Wt[n][k] = W[k][n] ------------
__global__ void transpose_w(const void* __restrict__ Wv,
                            unsigned short* __restrict__ Wt,
                            const int* __restrict__ flags) {
    __shared__ unsigned short tile[32][33];
    const bool fb = flags[0] != 0;
    int bx = blockIdx.x * 32, by = blockIdx.y * 32;
    int tx = threadIdx.x, ty = threadIdx.y;           // block 32x8
    if (fb) {
        const unsigned short* W = (const unsigned short*)Wv;
        for (int r = ty; r < 32; r += 8)
            tile[r][tx] = W[(by + r) * DIM + bx + tx];
    } else {
        const float* W = (const float*)Wv;
        for (int r = ty; r < 32; r += 8)
            tile[r][tx] = (unsigned short)f2bfu(W[(by + r) * DIM + bx + tx]);
    }
    __syncthreads();
    for (int r = ty; r < 32; r += 8)
        Wt[(bx + r) * DIM + by + tx] = tile[tx][r];
}

// ---------------- GEMM: hidden = X @ W  (canonical bf16 out, fp32 acc) --------
#define TM 128
#define TN 128
#define BK 32
#define LP 40   // padded LDS row length (elements) — conflict-free for b128 reads

__global__ __launch_bounds__(256) void gemm_kernel(
        const void* __restrict__ Xv,
        const unsigned short* __restrict__ Xc,
        const int have_xc,
        const unsigned short* __restrict__ Wt,
        unsigned short* __restrict__ H,
        const int* __restrict__ flags) {
    __shared__ unsigned short lA[TM * LP];
    __shared__ unsigned short lB[TN * LP];

    const bool fb = flags[0] != 0;
    const bool bfp = fb || (have_xc != 0);             // bf16 staging path?
    const unsigned short* Xb = fb ? (const unsigned short*)Xv : Xc;
    const float*          Xf = (const float*)Xv;

    const int t = threadIdx.x;
    const int mBase = blockIdx.y * TM;
    const int nBase = blockIdx.x * TN;
    const int w = t >> 6, lane = t & 63;
    const int lr = lane & 15, quad = lane >> 4;
    const int wr = w >> 1, wc = w & 1;

    v4f acc[4][4];
    #pragma unroll
    for (int i = 0; i < 4; ++i)
        #pragma unroll
        for (int j = 0; j < 4; ++j) acc[i][j] = (v4f)0.0f;

    for (int k0 = 0; k0 < DIM; k0 += BK) {
        #pragma unroll
        for (int rep = 0; rep < 2; ++rep) {
            int idx = rep * 256 + t;
            int r = idx >> 2;
            int cc = (idx & 3) * 8;
            int grow = mBase + r; if (grow >= N_NODES) grow = N_NODES - 1;
            size_t goff = (size_t)grow * DIM + k0 + cc;
            if (bfp) {
                uint4 av = *(const uint4*)(Xb + goff);
                *(uint4*)(&lA[r * LP + cc]) = av;
            } else {
                float4 a0 = *(const float4*)(Xf + goff);
                float4 a1 = *(const float4*)(Xf + goff + 4);
                uint4 av;
                av.x = f2bfu(a0.x) | (f2bfu(a0.y) << 16);
                av.y = f2bfu(a0.z) | (f2bfu(a0.w) << 16);
                av.z = f2bfu(a1.x) | (f2bfu(a1.y) << 16);
                av.w = f2bfu(a1.z) | (f2bfu(a1.w) << 16);
                *(uint4*)(&lA[r * LP + cc]) = av;
            }
            uint4 bv = *(const uint4*)(Wt + (size_t)(nBase + r) * DIM + k0 + cc);
            *(uint4*)(&lB[r * LP + cc]) = bv;
        }
        __syncthreads();

        short8 bfr[4];
        #pragma unroll
        for (int j = 0; j < 4; ++j)
            bfr[j] = *(const short8*)(&lB[(wc * 64 + j * 16 + lr) * LP + quad * 8]);
        #pragma unroll
        for (int i = 0; i < 4; ++i) {
            short8 a = *(const short8*)(&lA[(wr * 64 + i * 16 + lr) * LP + quad * 8]);
            #pragma unroll
            for (int j = 0; j < 4; ++j)
                acc[i][j] = __builtin_amdgcn_mfma_f32_16x16x32_bf16(a, bfr[j], acc[i][j], 0, 0, 0);
        }
        __syncthreads();
    }

    // epilogue: D[m][n]: n = lane&15, m = quad*4 + reg
    #pragma unroll
    for (int i = 0; i < 4; ++i) {
        #pragma unroll
        for (int j = 0; j < 4; ++j) {
            #pragma unroll
            for (int r = 0; r < 4; ++r) {
                int gm = mBase + wr * 64 + i * 16 + quad * 4 + r;
                int gn = nBase + wc * 64 + j * 16 + lr;
                if (gm < N_NODES)
                    H[(size_t)gm * DIM + gn] = (unsigned short)f2bfu(acc[i][j][r]);
            }
        }
    }
}

// ---------------- counting sort: hist / scan / scatter ------------------------
__global__ void hist_kernel(const int* __restrict__ row, int* __restrict__ cnt,
                            const int* __restrict__ flags) {
    const bool f64 = flags[1] != 0;
    int i = blockIdx.x * 256 + threadIdx.x;
    if (i < N_EDGES) {
        int r = f64 ? row[2 * (size_t)i] : row[i];
        atomicAdd(&cnt[r], 1);
    }
}

__global__ __launch_bounds__(256) void scan1_kernel(const int* __restrict__ cnt,
                                                    int* __restrict__ bsum) {
    __shared__ int sh[256];
    const int b = blockIdx.x, t = threadIdx.x;
    int base = b * 1024 + t * 4;
    int s = 0;
    #pragma unroll
    for (int k = 0; k < 4; ++k) {
        int i = base + k;
        if (i < N_NODES) s += cnt[i];
    }
    sh[t] = s;
    __syncthreads();
    for (int off = 128; off > 0; off >>= 1) {
        if (t < off) sh[t] += sh[t + off];
        __syncthreads();
    }
    if (t == 0) bsum[b] = sh[0];
}

// scan3 also folds in the cross-block offset (old scan2)
__global__ __launch_bounds__(256) void scan3_kernel(const int* __restrict__ cnt,
                                                    const int* __restrict__ bsum,
                                                    int* __restrict__ start,
                                                    int* __restrict__ cursor) {
    __shared__ int sh[256];
    __shared__ int boffs;
    const int b = blockIdx.x, t = threadIdx.x;
    if (t == 0) {
        int r = 0;
        #pragma unroll 8
        for (int i = 0; i < b; ++i) r += bsum[i];
        boffs = r;
        if (b == 0) start[N_NODES] = N_EDGES;
    }
    int base = b * 1024 + t * 4;
    int v[4];
    #pragma unroll
    for (int k = 0; k < 4; ++k) {
        int i = base + k;
        v[k] = (i < N_NODES) ? cnt[i] : 0;
    }
    int tsum = v[0] + v[1] + v[2] + v[3];
    sh[t] = tsum;
    __syncthreads();
    for (int off = 1; off < 256; off <<= 1) {
        int x = (t >= off) ? sh[t - off] : 0;
        __syncthreads();
        sh[t] += x;
        __syncthreads();
    }
    int excl = sh[t] - tsum + boffs;
    #pragma unroll
    for (int k = 0; k < 4; ++k) {
        int i = base + k;
        if (i < N_NODES) { start[i] = excl; cursor[i] = excl; }
        excl += v[k];
    }
}

__global__ void scatter_kernel(const int* __restrict__ row, const int* __restrict__ col,
                               const void* __restrict__ valv,
                               int* __restrict__ cursor,
                               int2* __restrict__ sCV,
                               const int* __restrict__ flags) {
    const bool fb  = flags[0] != 0;
    const bool f64 = flags[1] != 0;
    int i = blockIdx.x * 256 + threadIdx.x;
    if (i < N_EDGES) {
        int r = f64 ? row[2 * (size_t)i] : row[i];
        int c = f64 ? col[2 * (size_t)i] : col[i];
        float v = fb ? bf2f(((const unsigned short*)valv)[i])
                     : ((const float*)valv)[i];
        int p = atomicAdd(&cursor[r], 1);
        int2 cv; cv.x = c; cv.y = __float_as_int(v);
        sCV[p] = cv;
    }
}

// ---------------- gather: out[i] = sum_e val * hidden[col] + bias -------------
// One wave (64 lanes) per node; 4 nodes per 256-thread block.
// Per 64-edge chunk: one coalesced 512B wave-load of (col,val) metadata, then
// v_readlane broadcasts -> all H-row addresses known up-front -> unroll-4
// issues independent 1KB global_load_dwordx4 row reads (max MLP).
__global__ __launch_bounds__(256) void gather_kernel(
        const int* __restrict__ start, const int2* __restrict__ sCV,
        const unsigned short* __restrict__ H,
        const void* __restrict__ biasv, void* __restrict__ outv,
        const int* __restrict__ flags) {
    const bool fb = flags[0] != 0;
    const int lane = threadIdx.x & 63;
    const int node = blockIdx.x * 4 + (threadIdx.x >> 6);
    if (node >= N_NODES) return;
    const int s = start[node], e = start[node + 1];

    float a0 = 0.f, a1 = 0.f, a2 = 0.f, a3 = 0.f;
    float a4 = 0.f, a5 = 0.f, a6 = 0.f, a7 = 0.f;

    for (int p0 = s; p0 < e; p0 += 64) {
        int idx = p0 + lane;
        int clamped = (idx < e) ? idx : (e - 1);      // e > s here, safe
        int2 cv = sCV[clamped];                        // 512B coalesced batch
        int cnt = e - p0; if (cnt > 64) cnt = 64;
        #pragma unroll 4
        for (int q = 0; q < cnt; ++q) {
            int col  = __builtin_amdgcn_readlane(cv.x, q);   // SGPR, wave-uniform
            float v  = __int_as_float(__builtin_amdgcn_readlane(cv.y, q));
            uint4 h = *((const uint4*)(H + ((size_t)col << 9)) + lane);  // 16B/lane
            a0 = fmaf(v, lo16(h.x), a0);
            a1 = fmaf(v, hi16(h.x), a1);
            a2 = fmaf(v, lo16(h.y), a2);
            a3 = fmaf(v, hi16(h.y), a3);
            a4 = fmaf(v, lo16(h.z), a4);
            a5 = fmaf(v, hi16(h.z), a5);
            a6 = fmaf(v, lo16(h.w), a6);
            a7 = fmaf(v, hi16(h.w), a7);
        }
    }

    if (fb) {
        uint4 bb = *((const uint4*)biasv + lane);
        a0 += lo16(bb.x); a1 += hi16(bb.x);
        a2 += lo16(bb.y); a3 += hi16(bb.y);
        a4 += lo16(bb.z); a5 += hi16(bb.z);
        a6 += lo16(bb.w); a7 += hi16(bb.w);
        uint4 o;
        o.x = f2bfu(a0) | (f2bfu(a1) << 16);
        o.y = f2bfu(a2) | (f2bfu(a3) << 16);
        o.z = f2bfu(a4) | (f2bfu(a5) << 16);
        o.w = f2bfu(a6) | (f2bfu(a7) << 16);
        *((uint4*)((unsigned short*)outv + (size_t)node * DIM) + lane) = o;
    } else {
        const float4* bp = (const float4*)biasv + lane * 2;
        float4 b0 = bp[0], b1 = bp[1];
        float4 o0, o1;
        o0.x = a0 + b0.x; o0.y = a1 + b0.y; o0.z = a2 + b0.z; o0.w = a3 + b0.w;
        o1.x = a4 + b1.x; o1.y = a5 + b1.y; o1.z = a6 + b1.z; o1.w = a7 + b1.w;
        float4* op = (float4*)((float*)outv + (size_t)node * DIM) + lane * 2;
        op[0] = o0; op[1] = o1;
    }
}

extern "C" void kernel_launch(void* const* d_in, const int* in_sizes, int n_in,
                              void* d_out, int out_size, void* d_ws, size_t ws_size,
                              hipStream_t stream) {
    const void* X    = d_in[0];
    const void* W    = d_in[1];
    const void* bias = d_in[2];
    const void* eval = d_in[3];
    const int*  erow = (const int*)d_in[4];
    const int*  ecol = (const int*)d_in[5];

    char* w = (char*)d_ws;
    size_t o = 0;
    int* flags = (int*)(w + o); o += 256;
    unsigned short* hidden = (unsigned short*)(w + o); o += (size_t)N_NODES * DIM * 2;  // 51.2 MB
    int2*  sCV    = (int2*)(w + o);  o += (size_t)N_EDGES * 8;                          // 12.8 MB
    int*   cnt    = (int*)(w + o);   o += 200704;
    int*   start  = (int*)(w + o);   o += 200704;
    int*   cursor = (int*)(w + o);   o += 200704;
    unsigned short* Wt = (unsigned short*)(w + o); o += (size_t)DIM * DIM * 2;          // 0.5 MB
    int*   bsum   = (int*)(w + o);   o += 256;
    size_t base_end = o;
    unsigned short* Xc = (unsigned short*)(w + o);
    size_t need_xc = base_end + (size_t)N_NODES * DIM * 2;                              // +51.2 MB
    const int have_xc = (ws_size >= need_xc) ? 1 : 0;

    hipMemsetAsync(cnt, 0, N_NODES * sizeof(int), stream);

    detect_kernel<<<1, 256, 0, stream>>>((const unsigned int*)X, erow, flags);
    if (have_xc)
        convert_x<<<(N_NODES * DIM) / (256 * 8), 256, 0, stream>>>(X, Xc, flags);
    transpose_w<<<dim3(16, 16), dim3(32, 8), 0, stream>>>(W, Wt, flags);
    gemm_kernel<<<dim3(DIM / TN, (N_NODES + TM - 1) / TM), 256, 0, stream>>>(
        X, Xc, have_xc, Wt, hidden, flags);
    hist_kernel<<<(N_EDGES + 255) / 256, 256, 0, stream>>>(erow, cnt, flags);
    scan1_kernel<<<SCAN_NB, 256, 0, stream>>>(cnt, bsum);
    scan3_kernel<<<SCAN_NB, 256, 0, stream>>>(cnt, bsum, start, cursor);
    scatter_kernel<<<(N_EDGES + 255) / 256, 256, 0, stream>>>(erow, ecol, eval, cursor, sCV, flags);
    gather_kernel<<<(N_NODES + 3) / 4, 256, 0, stream>>>(start, sCV, hidden, bias, d_out, flags);
}

// Round 2
// 672.482 us; speedup vs baseline: 1.0343x; 1.0289x over previous
//
#include <hip/hip_runtime.h>

typedef short short8 __attribute__((ext_vector_type(8)));
typedef float v4f   __attribute__((ext_vector_type(4)));

#define N_NODES 50000
#define N_EDGES 1600000
#define DIM     512
#define SCAN_NB 49   // 49 blocks * 1024 elems = 50176 >= 50000
#define GNB     2048 // gather blocks: 2048*4 waves = 8192 = exact chip residency

__device__ __forceinline__ float bf2f(unsigned short u) {
    unsigned int x = ((unsigned int)u) << 16;
    return __uint_as_float(x);
}
__device__ __forceinline__ unsigned int f2bfu(float f) {
    unsigned int x = __float_as_uint(f);
    unsigned int r = x + 0x7fffu + ((x >> 16) & 1u);   // RTNE
    return r >> 16;
}
// bf16 pair unpack straight from a dword (no ushort round-trip)
__device__ __forceinline__ float lo16(unsigned int u) { return __uint_as_float(u << 16); }
__device__ __forceinline__ float hi16(unsigned int u) { return __uint_as_float(u & 0xffff0000u); }

__device__ __forceinline__ unsigned long long shfl64_xor(unsigned long long v, int m) {
    int lo = (int)(v & 0xffffffffull);
    int hi = (int)(v >> 32);
    lo = __shfl_xor(lo, m);
    hi = __shfl_xor(hi, m);
    return ((unsigned long long)(unsigned int)hi << 32) | (unsigned int)lo;
}

__device__ __forceinline__ void gload_lds16(const void* g, void* l) {
    __builtin_amdgcn_global_load_lds(
        (const __attribute__((address_space(1))) unsigned int*)g,
        (__attribute__((address_space(3))) unsigned int*)l, 16, 0, 0);
}

// ---------------- dtype detection --------------------------------------------
// flags[0] = 1 if float tensors are bf16 (else fp32)
// flags[1] = 1 if edge index tensors are int64 (else int32)
__global__ void detect_kernel(const unsigned int* __restrict__ xw,
                              const int* __restrict__ erow,
                              int* __restrict__ flags) {
    __shared__ int cbf, cz;
    if (threadIdx.x == 0) { cbf = 0; cz = 0; }
    __syncthreads();
    int lb = 0, lz = 0;
    for (int i = threadIdx.x; i < 1024; i += 256) {
        unsigned int w = xw[i];
        unsigned int e0 = (w >> 7) & 0xFFu;    // bf16 exponent of low half
        unsigned int e1 = (w >> 23) & 0xFFu;   // bf16 exponent of high half
        if (e0 >= 0x70u && e0 <= 0x8Fu && e1 >= 0x70u && e1 <= 0x8Fu) lb++;
        if (erow[2 * i + 1] == 0) lz++;
    }
    atomicAdd(&cbf, lb);
    atomicAdd(&cz, lz);
    __syncthreads();
    if (threadIdx.x == 0) {
        flags[0] = (cbf > 512) ? 1 : 0;
        flags[1] = (cz > 512) ? 1 : 0;
    }
}

// ---------------- X fp32 -> bf16 pre-convert (skipped if X already bf16) ------
__global__ __launch_bounds__(256) void convert_x(const void* __restrict__ Xv,
                                                 unsigned short* __restrict__ Xc,
                                                 const int* __restrict__ flags) {
    if (flags[0] != 0) return;   // data-dependent, stable across calls
    const float* Xf = (const float*)Xv;
    size_t i = ((size_t)blockIdx.x * 256 + threadIdx.x) * 8;
    float4 f0 = *(const float4*)(Xf + i);
    float4 f1 = *(const float4*)(Xf + i + 4);
    uint4 o;
    o.x = f2bfu(f0.x) | (f2bfu(f0.y) << 16);
    o.y = f2bfu(f0.z) | (f2bfu(f0.w) << 16);
    o.z = f2bfu(f1.x) | (f2bfu(f1.y) << 16);
    o.w = f2bfu(f1.z) | (f2bfu(f1.w) << 16);
    *(uint4*)(Xc + i) = o;
}

// ---------------- W transpose -> canonical bf16 Wt[n][k] = W[k][n] ------------
__global__ void transpose_w(const void* __restrict__ Wv,
                            unsigned short* __restrict__ Wt,
                            const int* __restrict__ flags) {
    __shared__ unsigned short tile[32][33];
    const bool fb = flags[0] != 0;
    int bx = blockIdx.x * 32, by = blockIdx.y * 32;
    int tx = threadIdx.x, ty = threadIdx.y;           // block 32x8
    if (fb) {
        const unsigned short* W = (const unsigned short*)Wv;
        for (int r = ty; r < 32; r += 8)
            tile[r][tx] = W[(by + r) * DIM + bx + tx];
    } else {
        const float* W = (const float*)Wv;
        for (int r = ty; r < 32; r += 8)
            tile[r][tx] = (unsigned short)f2bfu(W[(by + r) * DIM + bx + tx]);
    }
    __syncthreads();
    for (int r = ty; r < 32; r += 8)
        Wt[(bx + r) * DIM + by + tx] = tile[tx][r];
}

// ---------------- GEMM: hidden = X @ W  (m97 structure: global_load_lds) ------
#define TM 128
#define TN 128
#define BK 32

__global__ __launch_bounds__(256) void gemm_kernel(
        const void* __restrict__ Xv,
        const unsigned short* __restrict__ Xc,
        const int have_xc,
        const unsigned short* __restrict__ Wt,
        unsigned short* __restrict__ H,
        const int* __restrict__ flags) {
    __shared__ unsigned short lA[TM * BK];   // linear [128][32] — required by gload_lds
    __shared__ unsigned short lB[TN * BK];

    const bool fb = flags[0] != 0;
    const bool bfp = fb || (have_xc != 0);             // bf16 staging path?
    const unsigned short* Xb = fb ? (const unsigned short*)Xv : Xc;
    const float*          Xf = (const float*)Xv;

    const int t = threadIdx.x;
    const int mBase = blockIdx.y * TM;
    const int nBase = blockIdx.x * TN;
    const int w = t >> 6, lane = t & 63;
    const int lr = lane & 15, quad = lane >> 4;
    const int wr = w >> 1, wc = w & 1;

    v4f acc[4][4];
    #pragma unroll
    for (int i = 0; i < 4; ++i)
        #pragma unroll
        for (int j = 0; j < 4; ++j) acc[i][j] = (v4f)0.0f;

    for (int k0 = 0; k0 < DIM; k0 += BK) {
        // ---- stage B (always bf16) via global_load_lds: wave w covers rows w*32..+32
        #pragma unroll
        for (int r = 0; r < 2; ++r) {
            int chunk = w * 2 + r;                 // 0..7, 16 rows each
            int row = chunk * 16 + (lane >> 2);    // 0..127
            const unsigned short* gB = Wt + (size_t)(nBase + row) * DIM + k0 + (lane & 3) * 8;
            gload_lds16(gB, lB + chunk * 512);     // lane l -> lds +l*16B (linear)
        }
        // ---- stage A
        if (bfp) {
            #pragma unroll
            for (int r = 0; r < 2; ++r) {
                int chunk = w * 2 + r;
                int row = chunk * 16 + (lane >> 2);
                int grow = mBase + row; if (grow >= N_NODES) grow = N_NODES - 1;
                const unsigned short* gA = Xb + (size_t)grow * DIM + k0 + (lane & 3) * 8;
                gload_lds16(gA, lA + chunk * 512);
            }
        } else {
            // fp32 fallback: convert in VGPRs, ds_write into the same linear layout
            #pragma unroll
            for (int rep = 0; rep < 2; ++rep) {
                int idx = rep * 256 + t;
                int r = idx >> 2;
                int cc = (idx & 3) * 8;
                int grow = mBase + r; if (grow >= N_NODES) grow = N_NODES - 1;
                size_t goff = (size_t)grow * DIM + k0 + cc;
                float4 a0 = *(const float4*)(Xf + goff);
                float4 a1 = *(const float4*)(Xf + goff + 4);
                uint4 av;
                av.x = f2bfu(a0.x) | (f2bfu(a0.y) << 16);
                av.y = f2bfu(a0.z) | (f2bfu(a0.w) << 16);
                av.z = f2bfu(a1.x) | (f2bfu(a1.y) << 16);
                av.w = f2bfu(a1.z) | (f2bfu(a1.w) << 16);
                *(uint4*)(&lA[r * BK + cc]) = av;
            }
        }
        __syncthreads();

        short8 bfr[4];
        #pragma unroll
        for (int j = 0; j < 4; ++j)
            bfr[j] = *(const short8*)(&lB[(wc * 64 + j * 16 + lr) * BK + quad * 8]);
        #pragma unroll
        for (int i = 0; i < 4; ++i) {
            short8 a = *(const short8*)(&lA[(wr * 64 + i * 16 + lr) * BK + quad * 8]);
            #pragma unroll
            for (int j = 0; j < 4; ++j)
                acc[i][j] = __builtin_amdgcn_mfma_f32_16x16x32_bf16(a, bfr[j], acc[i][j], 0, 0, 0);
        }
        __syncthreads();
    }

    // epilogue: D[m][n]: n = lane&15, m = quad*4 + reg
    #pragma unroll
    for (int i = 0; i < 4; ++i) {
        #pragma unroll
        for (int j = 0; j < 4; ++j) {
            #pragma unroll
            for (int r = 0; r < 4; ++r) {
                int gm = mBase + wr * 64 + i * 16 + quad * 4 + r;
                int gn = nBase + wc * 64 + j * 16 + lr;
                if (gm < N_NODES)
                    H[(size_t)gm * DIM + gn] = (unsigned short)f2bfu(acc[i][j][r]);
            }
        }
    }
}

// ---------------- counting sort: hist / scan / scatter ------------------------
__global__ void hist_kernel(const int* __restrict__ row, int* __restrict__ cnt,
                            const int* __restrict__ flags) {
    const bool f64 = flags[1] != 0;
    int i = blockIdx.x * 256 + threadIdx.x;
    if (i < N_EDGES) {
        int r = f64 ? ((const int2*)row)[i].x : row[i];
        atomicAdd(&cnt[r], 1);
    }
}

__global__ __launch_bounds__(256) void scan1_kernel(const int* __restrict__ cnt,
                                                    int* __restrict__ bsum) {
    __shared__ int sh[256];
    const int b = blockIdx.x, t = threadIdx.x;
    int base = b * 1024 + t * 4;
    int s = 0;
    #pragma unroll
    for (int k = 0; k < 4; ++k) {
        int i = base + k;
        if (i < N_NODES) s += cnt[i];
    }
    sh[t] = s;
    __syncthreads();
    for (int off = 128; off > 0; off >>= 1) {
        if (t < off) sh[t] += sh[t + off];
        __syncthreads();
    }
    if (t == 0) bsum[b] = sh[0];
}

// scan3 also folds in the cross-block offset (old scan2)
__global__ __launch_bounds__(256) void scan3_kernel(const int* __restrict__ cnt,
                                                    const int* __restrict__ bsum,
                                                    int* __restrict__ start,
                                                    int* __restrict__ cursor) {
    __shared__ int sh[256];
    __shared__ int boffs;
    const int b = blockIdx.x, t = threadIdx.x;
    if (t == 0) {
        int r = 0;
        #pragma unroll 8
        for (int i = 0; i < b; ++i) r += bsum[i];
        boffs = r;
        if (b == 0) start[N_NODES] = N_EDGES;
    }
    int base = b * 1024 + t * 4;
    int v[4];
    #pragma unroll
    for (int k = 0; k < 4; ++k) {
        int i = base + k;
        v[k] = (i < N_NODES) ? cnt[i] : 0;
    }
    int tsum = v[0] + v[1] + v[2] + v[3];
    sh[t] = tsum;
    __syncthreads();
    for (int off = 1; off < 256; off <<= 1) {
        int x = (t >= off) ? sh[t - off] : 0;
        __syncthreads();
        sh[t] += x;
        __syncthreads();
    }
    int excl = sh[t] - tsum + boffs;
    #pragma unroll
    for (int k = 0; k < 4; ++k) {
        int i = base + k;
        if (i < N_NODES) { start[i] = excl; cursor[i] = excl; }
        excl += v[k];
    }
}

__global__ void scatter_kernel(const int* __restrict__ row, const int* __restrict__ col,
                               const void* __restrict__ valv,
                               int* __restrict__ cursor,
                               int2* __restrict__ sCV,
                               const int* __restrict__ flags) {
    const bool fb  = flags[0] != 0;
    const bool f64 = flags[1] != 0;
    int i = blockIdx.x * 256 + threadIdx.x;
    if (i < N_EDGES) {
        int r = f64 ? ((const int2*)row)[i].x : row[i];
        int c = f64 ? ((const int2*)col)[i].x : col[i];
        float v = fb ? bf2f(((const unsigned short*)valv)[i])
                     : ((const float*)valv)[i];
        int p = atomicAdd(&cursor[r], 1);
        int2 cv; cv.x = c; cv.y = __float_as_int(v);
        sCV[p] = cv;
    }
}

// ---------------- gather: out[i] = sum_e val * hidden[col] + bias -------------
// One wave per node, persistent grid (2048 blocks * 4 waves = exact residency).
// Each 64-edge chunk is bitonic-sorted by col in-wave so all co-resident waves
// sweep H in ascending-col order together -> chip-wide instantaneous working
// set shrinks from 51MB to a sliding window -> L2/L3 hits instead of HBM.
__global__ __launch_bounds__(256, 8) void gather_kernel(
        const int* __restrict__ start, const int2* __restrict__ sCV,
        const unsigned short* __restrict__ H,
        const void* __restrict__ biasv, void* __restrict__ outv,
        const int* __restrict__ flags) {
    const bool fb = flags[0] != 0;
    const int lane = threadIdx.x & 63;
    const int wv = threadIdx.x >> 6;

    // hoist bias (uniform across nodes)
    float b0v = 0, b1v = 0, b2v = 0, b3v = 0, b4v = 0, b5v = 0, b6v = 0, b7v = 0;
    if (fb) {
        uint4 bb = *((const uint4*)biasv + lane);
        b0v = lo16(bb.x); b1v = hi16(bb.x);
        b2v = lo16(bb.y); b3v = hi16(bb.y);
        b4v = lo16(bb.z); b5v = hi16(bb.z);
        b6v = lo16(bb.w); b7v = hi16(bb.w);
    } else {
        const float4* bp = (const float4*)biasv + lane * 2;
        float4 f0 = bp[0], f1 = bp[1];
        b0v = f0.x; b1v = f0.y; b2v = f0.z; b3v = f0.w;
        b4v = f1.x; b5v = f1.y; b6v = f1.z; b7v = f1.w;
    }

    for (int node = blockIdx.x * 4 + wv; node < N_NODES; node += GNB * 4) {
        const int s = start[node], e = start[node + 1];

        float a0 = 0.f, a1 = 0.f, a2 = 0.f, a3 = 0.f;
        float a4 = 0.f, a5 = 0.f, a6 = 0.f, a7 = 0.f;

        for (int p0 = s; p0 < e; p0 += 64) {
            int idx = p0 + lane;
            unsigned long long key;
            if (idx < e) {
                int2 cv = sCV[idx];                  // 512B coalesced batch
                key = ((unsigned long long)(unsigned int)cv.x << 32) | (unsigned int)cv.y;
            } else {
                key = ~0ull;                          // sentinel sorts last
            }
            // 64-lane bitonic sort ascending by (col,valbits)
            #pragma unroll
            for (int k = 2; k <= 64; k <<= 1) {
                #pragma unroll
                for (int j = k >> 1; j > 0; j >>= 1) {
                    unsigned long long other = shfl64_xor(key, j);
                    bool keep_min = (((lane & j) == 0) == ((lane & k) == 0));
                    unsigned long long mn = (key < other) ? key : other;
                    unsigned long long mx = (key < other) ? other : key;
                    key = keep_min ? mn : mx;
                }
            }
            int cnt = e - p0; if (cnt > 64) cnt = 64;
            int klo = (int)(key & 0xffffffffull);
            int khi = (int)(key >> 32);
            #pragma unroll 4
            for (int q = 0; q < cnt; ++q) {
                int col  = __builtin_amdgcn_readlane(khi, q);   // SGPR, wave-uniform
                float v  = __int_as_float(__builtin_amdgcn_readlane(klo, q));
                uint4 h = *((const uint4*)(H + ((size_t)(unsigned int)col << 9)) + lane);
                a0 = fmaf(v, lo16(h.x), a0);
                a1 = fmaf(v, hi16(h.x), a1);
                a2 = fmaf(v, lo16(h.y), a2);
                a3 = fmaf(v, hi16(h.y), a3);
                a4 = fmaf(v, lo16(h.z), a4);
                a5 = fmaf(v, hi16(h.z), a5);
                a6 = fmaf(v, lo16(h.w), a6);
                a7 = fmaf(v, hi16(h.w), a7);
            }
        }

        if (fb) {
            uint4 o;
            o.x = f2bfu(a0 + b0v) | (f2bfu(a1 + b1v) << 16);
            o.y = f2bfu(a2 + b2v) | (f2bfu(a3 + b3v) << 16);
            o.z = f2bfu(a4 + b4v) | (f2bfu(a5 + b5v) << 16);
            o.w = f2bfu(a6 + b6v) | (f2bfu(a7 + b7v) << 16);
            *((uint4*)((unsigned short*)outv + (size_t)node * DIM) + lane) = o;
        } else {
            float4 o0, o1;
            o0.x = a0 + b0v; o0.y = a1 + b1v; o0.z = a2 + b2v; o0.w = a3 + b3v;
            o1.x = a4 + b4v; o1.y = a5 + b5v; o1.z = a6 + b6v; o1.w = a7 + b7v;
            float4* op = (float4*)((float*)outv + (size_t)node * DIM) + lane * 2;
            op[0] = o0; op[1] = o1;
        }
    }
}

extern "C" void kernel_launch(void* const* d_in, const int* in_sizes, int n_in,
                              void* d_out, int out_size, void* d_ws, size_t ws_size,
                              hipStream_t stream) {
    const void* X    = d_in[0];
    const void* W    = d_in[1];
    const void* bias = d_in[2];
    const void* eval = d_in[3];
    const int*  erow = (const int*)d_in[4];
    const int*  ecol = (const int*)d_in[5];

    char* w = (char*)d_ws;
    size_t o = 0;
    int* flags = (int*)(w + o); o += 256;
    unsigned short* hidden = (unsigned short*)(w + o); o += (size_t)N_NODES * DIM * 2;  // 51.2 MB
    int2*  sCV    = (int2*)(w + o);  o += (size_t)N_EDGES * 8;                          // 12.8 MB
    int*   cnt    = (int*)(w + o);   o += 200704;
    int*   start  = (int*)(w + o);   o += 200704;
    int*   cursor = (int*)(w + o);   o += 200704;
    unsigned short* Wt = (unsigned short*)(w + o); o += (size_t)DIM * DIM * 2;          // 0.5 MB
    int*   bsum   = (int*)(w + o);   o += 256;
    size_t base_end = o;
    unsigned short* Xc = (unsigned short*)(w + o);
    size_t need_xc = base_end + (size_t)N_NODES * DIM * 2;                              // +51.2 MB
    const int have_xc = (ws_size >= need_xc) ? 1 : 0;

    hipMemsetAsync(cnt, 0, N_NODES * sizeof(int), stream);

    detect_kernel<<<1, 256, 0, stream>>>((const unsigned int*)X, erow, flags);
    if (have_xc)
        convert_x<<<(N_NODES * DIM) / (256 * 8), 256, 0, stream>>>(X, Xc, flags);
    transpose_w<<<dim3(16, 16), dim3(32, 8), 0, stream>>>(W, Wt, flags);
    gemm_kernel<<<dim3(DIM / TN, (N_NODES + TM - 1) / TM), 256, 0, stream>>>(
        X, Xc, have_xc, Wt, hidden, flags);
    hist_kernel<<<(N_EDGES + 255) / 256, 256, 0, stream>>>(erow, cnt, flags);
    scan1_kernel<<<SCAN_NB, 256, 0, stream>>>(cnt, bsum);
    scan3_kernel<<<SCAN_NB, 256, 0, stream>>>(cnt, bsum, start, cursor);
    scatter_kernel<<<(N_EDGES + 255) / 256, 256, 0, stream>>>(erow, ecol, eval, cursor, sCV, flags);
    gather_kernel<<<GNB, 256, 0, stream>>>(start, sCV, hidden, bias, d_out, flags);
}